// Round 5
// baseline (502.214 us; speedup 1.0000x reference)
//
#include <hip/hip_runtime.h>
#include <math.h>

#define NNODES 1024
#define EB 4          // edges per tile (one edge per wave in TP phase)
#define GRID 1024     // co-resident: 4 blocks/CU x 256 CUs

typedef __attribute__((ext_vector_type(8))) short short8;
typedef __attribute__((ext_vector_type(4))) float f32x4;

__device__ __forceinline__ unsigned short f2bf(float f) {
  union { float f; unsigned int u; } v; v.f = f;
  unsigned int r = v.u + 0x7fffu + ((v.u >> 16) & 1u);
  return (unsigned short)(r >> 16);
}

// =====================================================================
// Host-side constants (pure CPU at static init — no HIP calls, graph-safe).
// CG tensors in f64 (matches reference), 0.25 agg-scale folded in.
// Passed as by-value kernarg -> wave-uniform s_loads.
// =====================================================================
struct CGPack { float v[576]; };

static const double H_SHC[16][2] = {
  {1.0, 0.0},
  {1.7320508075688772, 0.0},
  {1.7320508075688772, 0.0},
  {1.7320508075688772, 0.0},
  {3.8729833462074170, 0.0},
  {3.8729833462074170, 0.0},
  {3.3541019662496844, -1.1180339887498949},
  {3.8729833462074170, 0.0},
  {1.9364916731037085, -1.9364916731037085},
  {6.2749501990055667, -2.0916500663351889},
  {10.246950765959598, 0.0},
  {8.1009258730098255, -1.6201851746019651},
  {6.6143782776614768, -3.9686269665968861},
  {8.1009258730098255, -1.6201851746019651},
  {5.1234753829797990, -5.1234753829797990},
  {2.0916500663351889, -6.2749501990055667},
};
static const int H_SHE[16][2] = {     // exponents packed ex | ey<<4 | ez<<8
  {0,0},{1,0},{16,0},{256,0},
  {17,0},{272,0},{512,0},{257,0},{2,32},
  {18,48},{273,0},{528,16},{768,256},{513,1},{258,288},{3,33}};
static const int H_PL1[13] = {0,1,2, 0,1,1,2,3, 0,1,2,2,3};
static const int H_PL2[13] = {0,1,2, 1,0,2,1,2, 2,1,0,2,1};
static const int H_PL3[13] = {0,0,0, 1,1,1,1,1, 2,2,2,2,2};
static const int H_PCG[13] = {0,1,10, 35,44,53,98,143, 248,273,318,343,468};

static double h_dfact(int n) { double r = 1.0; while (n > 1) { r *= n; n -= 2; } return r; }

struct HostConsts {
  CGPack pack;
  float inv_actc;
  HostConsts() {
    const int LOFF[4] = {0,1,4,9};
    for (int p = 0; p < 13; p++) {
      int l1 = H_PL1[p], l2 = H_PL2[p], l3 = H_PL3[p];
      int n1 = 2*l1+1, n2 = 2*l2+1, n3 = 2*l3+1, nent = n1*n2*n3;
      double vals[125], ss = 0.0;
      for (int t = 0; t < nent; t++) {
        int i = t / (n2*n3);
        int rem = t - i*(n2*n3);
        int j = rem / n3;
        int k = rem - j*n3;
        int lm1 = LOFF[l1]+i, lm2 = LOFF[l2]+j, lm3 = LOFF[l3]+k;
        double v = 0.0;
        for (int t1 = 0; t1 < 2; t1++)
        for (int t2 = 0; t2 < 2; t2++)
        for (int t3 = 0; t3 < 2; t3++) {
          double cc = H_SHC[lm1][t1]*H_SHC[lm2][t2]*H_SHC[lm3][t3];
          if (cc == 0.0) continue;
          int s = H_SHE[lm1][t1] + H_SHE[lm2][t2] + H_SHE[lm3][t3];
          int a = s & 15, b = (s >> 4) & 15, c = (s >> 8) & 15;
          if (!((a|b|c) & 1))
            v += cc * (h_dfact(a-1)*h_dfact(b-1)*h_dfact(c-1) / h_dfact(a+b+c+1));
        }
        vals[t] = v; ss += v*v;
      }
      double scale = sqrt((double)(2*l3+1)) / sqrt(ss);
      for (int t = 0; t < nent; t++) pack.v[H_PCG[p]+t] = (float)(vals[t]*scale*0.25);
    }
    pack.v[573] = pack.v[574] = pack.v[575] = 0.f;
    double s = 0.0, dz = 24.0/200000.0;
    for (int i = 0; i <= 200000; i++) {
      double z = -12.0 + dz*i;
      double ph = exp(-0.5*z*z) * 0.39894228040143267794;
      double sl = z / (1.0 + exp(-z));
      s += sl*sl*ph;
    }
    inv_actc = (float)(1.0 / sqrt(s*dz));
  }
};

// ---------------- TP helper: fully unrolled with compile-time parity masking ----
template<int L1, int L2, int L3>
__device__ __forceinline__ void tp_path(const float* __restrict__ cgp,
    const float a[16], const float b[9], float o[2*L3+1])
{
  constexpr int N1 = 2*L1+1, N2 = 2*L2+1, N3 = 2*L3+1;
  constexpr int AO = (L1==0) ? 0 : (L1==1) ? 1 : (L1==2) ? 4 : 9;
  constexpr int BO = (L2==0) ? 0 : (L2==1) ? 1 : 4;
  constexpr int LM1 = (L1==0) ? 0 : (L1==1) ? 1 : (L1==2) ? 4 : 9;
  constexpr int LM2 = (L2==0) ? 0 : (L2==1) ? 1 : 4;
  constexpr int LM3 = (L3==0) ? 0 : (L3==1) ? 1 : 4;
  static constexpr unsigned char PAR[16] =
      {0, 1,2,4, 3,6,0,5,0, 2,7,2,4,1,4,1};
  #pragma unroll
  for (int k = 0; k < N3; k++) o[k] = 0.f;
  int ci = 0;
  #pragma unroll
  for (int i = 0; i < N1; i++) {
    #pragma unroll
    for (int j = 0; j < N2; j++) {
      float ab = a[AO+i] * b[BO+j];
      #pragma unroll
      for (int k = 0; k < N3; k++) {
        if ((PAR[LM1+i] ^ PAR[LM2+j] ^ PAR[LM3+k]) == 0)
          o[k] = fmaf(ab, cgp[ci], o[k]);
        ci++;
      }
    }
  }
}

// ---------------- device-scope grid barrier (counters zeroed by memset) ----
__device__ __forceinline__ void grid_bar(int* ctr, int nblk) {
  __syncthreads();
  if (threadIdx.x == 0) {
    __threadfence();   // release my block's writes to device scope
    __hip_atomic_fetch_add(ctr, 1, __ATOMIC_RELEASE, __HIP_MEMORY_SCOPE_AGENT);
    while (__hip_atomic_load(ctr, __ATOMIC_ACQUIRE, __HIP_MEMORY_SCOPE_AGENT) < nblk)
      __builtin_amdgcn_s_sleep(2);
    __threadfence();   // acquire other blocks' writes
  }
  __syncthreads();
}

// =====================================================================
// MEGA-KERNEL: one dispatch, 1024 co-resident blocks, 2 grid barriers.
//   Phase A: blocks 0-255 w=x@Ww GEMM | 256-287 weight pack | 288-351 scatter
//   Phase B: node aggregation (block = node)
//   Phase D: 4 edge-tiles per block (EB=4 proven structure)
// =====================================================================
__global__ __launch_bounds__(256, 4) void mega(
    const float* __restrict__ vec, const float* __restrict__ x,
    const float* __restrict__ V, const int* __restrict__ senders,
    const float* __restrict__ Ww,
    const float* __restrict__ Wv1, const float* __restrict__ Wv2,
    const float* __restrict__ W1, const float* __restrict__ W2, const float* __restrict__ W3,
    const CGPack P, float inv_actc,
    float* __restrict__ node_agg, float* __restrict__ w_ws,
    int* __restrict__ counts, int* __restrict__ elist, int* __restrict__ bars,
    unsigned short* __restrict__ wv1f, unsigned short* __restrict__ wv2f,
    unsigned short* __restrict__ w1f, unsigned short* __restrict__ w2f,
    unsigned short* __restrict__ w3f,
    float* __restrict__ out, int E)
{
  __shared__ __align__(16) unsigned short V12sh[32*328]; // 20992 B; aliased: xsh/red/vosh
  __shared__ __align__(16) unsigned short zrow[336];
  __shared__ __align__(16) unsigned short hsh[4*264];
  __shared__ __align__(16) unsigned short h1sh[4*72];
  __shared__ __align__(16) unsigned short h2sh[4*72];
  __shared__ __align__(16) float xosh[4*64];
  __shared__ float ush[EB];

  const int t = threadIdx.x;
  const int bid = blockIdx.x;
  const int wid = t >> 6, lane = t & 63;
  const int nblk = gridDim.x;

  // ================= Phase A =================
  if (bid < 256) {
    // ---- w-GEMM: 64 edges x 64 outputs, K=64, f32 ----
    float* xsh = (float*)V12sh;    // 16 KB
    const int eb0 = bid * 64;
    for (int q = t; q < 1024; q += 256)
      ((f32x4*)xsh)[q] = ((const f32x4*)(x + (size_t)eb0*64))[q];
    const int n = t & 63;
    float ww[64];
    #pragma unroll
    for (int f = 0; f < 64; f++) ww[f] = Ww[f*64 + n];
    __syncthreads();
    const int er0 = (t >> 6) * 16;
    #pragma unroll
    for (int i = 0; i < 16; i++) {
      int e = er0 + i;
      const f32x4* xr = (const f32x4*)(&xsh[e*64]);  // broadcast reads
      float a0 = 0.f, a1 = 0.f, a2 = 0.f, a3 = 0.f;
      #pragma unroll
      for (int fq = 0; fq < 16; fq += 4) {
        f32x4 x0 = xr[fq+0], x1 = xr[fq+1], x2 = xr[fq+2], x3 = xr[fq+3];
        a0 = fmaf(x0.x, ww[fq*4+0],  fmaf(x0.y, ww[fq*4+1],  fmaf(x0.z, ww[fq*4+2],  fmaf(x0.w, ww[fq*4+3],  a0))));
        a1 = fmaf(x1.x, ww[fq*4+4],  fmaf(x1.y, ww[fq*4+5],  fmaf(x1.z, ww[fq*4+6],  fmaf(x1.w, ww[fq*4+7],  a1))));
        a2 = fmaf(x2.x, ww[fq*4+8],  fmaf(x2.y, ww[fq*4+9],  fmaf(x2.z, ww[fq*4+10], fmaf(x2.w, ww[fq*4+11], a2))));
        a3 = fmaf(x3.x, ww[fq*4+12], fmaf(x3.y, ww[fq*4+13], fmaf(x3.z, ww[fq*4+14], fmaf(x3.w, ww[fq*4+15], a3))));
      }
      w_ws[(size_t)(eb0+e)*64 + n] = ((a0+a1)+(a2+a3)) * 0.125f;
    }
  } else if (bid < 288) {
    // ---- weight fragment pack: 4 fragments per block, scales folded ----
    const int g = (bid - 256)*4 + wid;
    const float ia = inv_actc;
    const float s320 = 0.05590169943749474f;  // 1/sqrt(320)
    const float* src; unsigned short* dst; int nk, f; float sc;
    if (g < 40)       { src = Wv1; dst = wv1f; nk = 10; f = g;       sc = s320; }
    else if (g < 80)  { src = Wv2; dst = wv2f; nk = 10; f = g - 40;  sc = s320; }
    else if (g < 112) { src = W1;  dst = w1f;  nk = 8;  f = g - 80;  sc = 0.0625f; }
    else if (g < 120) { src = W2;  dst = w2f;  nk = 2;  f = g - 112; sc = 0.125f*ia; }
    else              { src = W3;  dst = w3f;  nk = 2;  f = g - 120; sc = 0.125f*ia; }
    int nt = f / nk;
    int ks = f - nt*nk;
    unsigned short us[8];
    #pragma unroll
    for (int j = 0; j < 8; j++) {
      float v = src[(ks*32 + (lane>>4)*8 + j)*64 + nt*16 + (lane & 15)];
      us[j] = f2bf(v * sc);
    }
    uint4 pk;
    pk.x = (unsigned)us[0] | ((unsigned)us[1] << 16);
    pk.y = (unsigned)us[2] | ((unsigned)us[3] << 16);
    pk.z = (unsigned)us[4] | ((unsigned)us[5] << 16);
    pk.w = (unsigned)us[6] | ((unsigned)us[7] << 16);
    *(uint4*)(dst + ((size_t)f*64 + lane)*8) = pk;
  } else if (bid < 352) {
    // ---- scatter (counts pre-zeroed by memset) ----
    int e = (bid - 288)*256 + t;
    if (e < E) {
      int s = senders[e];
      int pos = atomicAdd(&counts[s], 1) & 63;  // P(deg>=64) ~ 1e-18 for Poisson(16)
      elist[s*64 + pos] = e;
    }
  }

  grid_bar(&bars[0], nblk);

  // ================= Phase B: node aggregation (block = node) =================
  {
    float* red = (float*)V12sh;    // 16 KB
    const int s = bid;
    const int deg = min(counts[s], 64);

    const float S3 = 1.7320508075688772f, S5 = 2.23606797749979f, S15 = 3.872983346207417f;
    const float C33 = 2.091650066335189f, C32 = 5.123475382979799f, C31 = 1.6201851746019651f;
    const float C30 = 1.3228756555322954f, CX = 10.246950765959598f;

    float A[16];
    #pragma unroll
    for (int k = 0; k < 16; k++) A[k] = 0.f;

    for (int ii = wid; ii < deg; ii += 4) {
      int e = elist[s*64 + ii];
      float wv = w_ws[(size_t)e*64 + lane];     // coalesced 256B/wave
      float vx = vec[e*3+0], vy = vec[e*3+1], vz = vec[e*3+2];
      float d = sqrtf(vx*vx + vy*vy + vz*vz);
      float X = vx/d, Yv = vy/d, Z = vz/d;
      float y[16];
      y[0] = 1.f;
      y[1] = S3*X;  y[2] = S3*Yv;  y[3] = S3*Z;
      y[4] = S15*X*Yv; y[5] = S15*Yv*Z; y[6] = 0.5f*S5*(3.f*Z*Z - 1.f);
      y[7] = S15*X*Z;  y[8] = 0.5f*S15*(X*X - Yv*Yv);
      y[9]  = C33*Yv*(3.f*X*X - Yv*Yv);
      y[10] = CX*X*Yv*Z;
      y[11] = C31*Yv*(5.f*Z*Z - 1.f);
      y[12] = C30*Z*(5.f*Z*Z - 3.f);
      y[13] = C31*X*(5.f*Z*Z - 1.f);
      y[14] = C32*Z*(X*X - Yv*Yv);
      y[15] = C33*X*(X*X - 3.f*Yv*Yv);
      #pragma unroll
      for (int k = 0; k < 16; k++) A[k] = fmaf(wv, y[k], A[k]);
    }
    #pragma unroll
    for (int k = 0; k < 16; k++) red[wid*1024 + lane*16 + k] = A[k];
    __syncthreads();
    f32x4 v0 = ((f32x4*)red)[t];
    f32x4 v1 = ((f32x4*)red)[256 + t];
    f32x4 v2 = ((f32x4*)red)[512 + t];
    f32x4 v3 = ((f32x4*)red)[768 + t];
    f32x4 sum = v0 + v1 + v2 + v3;
    ((f32x4*)(node_agg + (size_t)s*1024))[t] = sum;
  }

  grid_bar(&bars[1], nblk);

  // ================= Phase D: 4 edge-tiles per block =================
  unsigned short* V1sh = V12sh;
  unsigned short* V2sh = V12sh + 12*328;
  float* vosh = (float*)V12sh;   // 4*584 floats = 9344 B <= 20992 B
  const float* cg = P.v;         // kernarg -> wave-uniform s_loads
  const size_t E64 = (size_t)E * 64;
  const int ntile = wid;
  const int qr = lane >> 4;
  const int ml = lane & 15;

  if (t < 168) ((unsigned int*)zrow)[t] = 0u;

  for (int it = 0; it < 4; ++it) {
    const int e0 = bid*16 + it*4;

    if (t < 64) {  // x -> hsh staging: 64 threads x 4 floats = 4 edges x 64 feats
      int el = t >> 4, off = (t & 15)*4;
      f32x4 xv = *(const f32x4*)(x + (size_t)(e0 + el)*64 + off);
      uint2 pk;
      pk.x = (unsigned)f2bf(xv.x) | ((unsigned)f2bf(xv.y) << 16);
      pk.y = (unsigned)f2bf(xv.z) | ((unsigned)f2bf(xv.w) << 16);
      *(uint2*)(hsh + el*264 + off) = pk;
    }

    // ---- TP phase: one edge per wave ----
    {
      const int eloc = wid;
      const int eg = e0 + eloc;

      float b[9];
      const float* vp = V + (size_t)eg*576 + lane*9;
      #pragma unroll
      for (int j = 0; j < 9; j++) b[j] = vp[j];

      const int s = senders[eg];
      float a[16];
      const f32x4* nap = (const f32x4*)(node_agg + s*1024 + lane*16);
      #pragma unroll
      for (int q = 0; q < 4; q++) {
        f32x4 av = nap[q];
        a[q*4+0] = av.x; a[q*4+1] = av.y; a[q*4+2] = av.z; a[q*4+3] = av.w;
      }

      float o1[1], o3[3], o5[5];
      tp_path<0,0,0>(cg + 0,  a, b, o1); hsh[eloc*264 + 64 + lane*3 + 0] = f2bf(o1[0]);
      tp_path<1,1,0>(cg + 1,  a, b, o1); hsh[eloc*264 + 64 + lane*3 + 1] = f2bf(o1[0]);
      tp_path<2,2,0>(cg + 10, a, b, o1); hsh[eloc*264 + 64 + lane*3 + 2] = f2bf(o1[0]);
      tp_path<0,1,1>(cg + 35, a, b, o3);
      { int r = eloc*3; for (int i=0;i<3;i++) V1sh[(r+i)*328 + 0*64 + lane] = f2bf(o3[i]); }
      tp_path<1,0,1>(cg + 44, a, b, o3);
      { int r = eloc*3; for (int i=0;i<3;i++) V1sh[(r+i)*328 + 1*64 + lane] = f2bf(o3[i]); }
      tp_path<1,2,1>(cg + 53, a, b, o3);
      { int r = eloc*3; for (int i=0;i<3;i++) V1sh[(r+i)*328 + 2*64 + lane] = f2bf(o3[i]); }
      tp_path<2,1,1>(cg + 98, a, b, o3);
      { int r = eloc*3; for (int i=0;i<3;i++) V1sh[(r+i)*328 + 3*64 + lane] = f2bf(o3[i]); }
      tp_path<3,2,1>(cg + 143, a, b, o3);
      { int r = eloc*3; for (int i=0;i<3;i++) V1sh[(r+i)*328 + 4*64 + lane] = f2bf(o3[i]); }
      tp_path<0,2,2>(cg + 248, a, b, o5);
      { int r = eloc*5; for (int i=0;i<5;i++) V2sh[(r+i)*328 + 0*64 + lane] = f2bf(o5[i]); }
      tp_path<1,1,2>(cg + 273, a, b, o5);
      { int r = eloc*5; for (int i=0;i<5;i++) V2sh[(r+i)*328 + 1*64 + lane] = f2bf(o5[i]); }
      tp_path<2,0,2>(cg + 318, a, b, o5);
      { int r = eloc*5; for (int i=0;i<5;i++) V2sh[(r+i)*328 + 2*64 + lane] = f2bf(o5[i]); }
      tp_path<2,2,2>(cg + 343, a, b, o5);
      { int r = eloc*5; for (int i=0;i<5;i++) V2sh[(r+i)*328 + 3*64 + lane] = f2bf(o5[i]); }
      tp_path<3,1,2>(cg + 468, a, b, o5);
      { int r = eloc*5; for (int i=0;i<5;i++) V2sh[(r+i)*328 + 4*64 + lane] = f2bf(o5[i]); }

      if (lane == 0) {
        float vx = vec[eg*3+0], vy = vec[eg*3+1], vz = vec[eg*3+2];
        float d = sqrtf(vx*vx + vy*vy + vz*vz);
        float u = 0.f;
        if (d < 1.f) {
          float d3 = d*d*d, d6 = d3*d3, d7 = d6*d, d8 = d7*d;
          u = 1.f - 28.f*d6 + 48.f*d7 - 21.f*d8;
        }
        ush[eloc] = u;
      }
    }
    __syncthreads();

    // ---- MFMA GEMM phase: wave wid owns output-column tile ntile (16 cols) ----
    // V1: M=12 (1 tile), K=320 (1/sqrt(320) folded into wv1f)
    f32x4 acc1 = (f32x4){0,0,0,0};
    {
      const unsigned short* p0 = (ml < 12) ? &V1sh[ml*328] : zrow;
      const unsigned short* bb = wv1f + ((size_t)(ntile*10)*64 + lane)*8;
      #pragma unroll
      for (int ks = 0; ks < 10; ks++) {
        short8 bf = *(const short8*)(bb + ks*512);
        short8 af = *(const short8*)(p0 + ks*32 + qr*8);
        acc1 = __builtin_amdgcn_mfma_f32_16x16x32_bf16(af, bf, acc1, 0, 0, 0);
      }
    }

    // V2: M=20 (2 tiles), K=320
    f32x4 acc2a = (f32x4){0,0,0,0}, acc2b = (f32x4){0,0,0,0};
    {
      const unsigned short* p0 = &V2sh[ml*328];
      const unsigned short* p1 = (16+ml < 20) ? &V2sh[(16+ml)*328] : zrow;
      const unsigned short* bb = wv2f + ((size_t)(ntile*10)*64 + lane)*8;
      #pragma unroll
      for (int ks = 0; ks < 10; ks++) {
        short8 bf = *(const short8*)(bb + ks*512);
        int ao = ks*32 + qr*8;
        short8 af0 = *(const short8*)(p0 + ao);
        short8 af1 = *(const short8*)(p1 + ao);
        acc2a = __builtin_amdgcn_mfma_f32_16x16x32_bf16(af0, bf, acc2a, 0, 0, 0);
        acc2b = __builtin_amdgcn_mfma_f32_16x16x32_bf16(af1, bf, acc2b, 0, 0, 0);
      }
    }

    // ---- MLP layer 1 (1/16 folded into w1f) ----
    {
      f32x4 c = (f32x4){0,0,0,0};
      const unsigned short* hp = (ml < 4) ? &hsh[ml*264] : zrow;
      const unsigned short* bb = w1f + ((size_t)(ntile*8)*64 + lane)*8;
      #pragma unroll
      for (int ks = 0; ks < 8; ks++) {
        short8 bf = *(const short8*)(bb + ks*512);
        short8 af = *(const short8*)(hp + ks*32 + qr*8);
        c = __builtin_amdgcn_mfma_f32_16x16x32_bf16(af, bf, c, 0, 0, 0);
      }
      #pragma unroll
      for (int r = 0; r < 4; r++) {
        int row = qr*4 + r;
        if (row < 4) {
          float v = c[r];
          float sv = v / (1.f + expf(-v));       // inv_actc folded into w2f
          h1sh[row*72 + ntile*16 + ml] = f2bf(sv);
        }
      }
    }
    __syncthreads();   // h1sh ready; ALL waves done reading V1sh/V2sh

    // ---- vosh staging over dead V12sh ----
    #pragma unroll
    for (int r = 0; r < 4; r++) {
      int row = qr*4 + r;
      if (row < 12) {
        int el = row / 3, i = row - (row/3)*3;
        vosh[el*584 + (ntile*16+ml)*9 + 1 + i] = acc1[r];
      }
    }
    #pragma unroll
    for (int r = 0; r < 4; r++) {
      int row = qr*4 + r;     // 0..15, all < 20
      int el = row / 5, i = row - (row/5)*5;
      vosh[el*584 + (ntile*16+ml)*9 + 4 + i] = acc2a[r];
    }
    #pragma unroll
    for (int r = 0; r < 4; r++) {
      int row = 16 + qr*4 + r;
      if (row < 20) {
        int el = row / 5, i = row - (row/5)*5;
        vosh[el*584 + (ntile*16+ml)*9 + 4 + i] = acc2b[r];
      }
    }
    { int el = t >> 6, o = t & 63;
      vosh[el*584 + o*9] = 0.f; }   // V_out channel 0 = 0

    // ---- MLP layer 2 (0.125*inv_actc folded into w2f) ----
    {
      f32x4 c = (f32x4){0,0,0,0};
      const unsigned short* ap = (ml < 4) ? &h1sh[ml*72] : zrow;
      const unsigned short* bb = w2f + ((size_t)(ntile*2)*64 + lane)*8;
      #pragma unroll
      for (int ks = 0; ks < 2; ks++) {
        short8 bf = *(const short8*)(bb + ks*512);
        short8 af = *(const short8*)(ap + ks*32 + qr*8);
        c = __builtin_amdgcn_mfma_f32_16x16x32_bf16(af, bf, c, 0, 0, 0);
      }
      #pragma unroll
      for (int r = 0; r < 4; r++) {
        int row = qr*4 + r;
        if (row < 4) {
          float v = c[r];
          float sv = v / (1.f + expf(-v));       // inv_actc folded into w3f
          h2sh[row*72 + ntile*16 + ml] = f2bf(sv);
        }
      }
    }
    __syncthreads();   // h2sh + vosh ready

    // ---- MLP layer 3 -> xosh ----
    {
      f32x4 c = (f32x4){0,0,0,0};
      const unsigned short* ap = (ml < 4) ? &h2sh[ml*72] : zrow;
      const unsigned short* bb = w3f + ((size_t)(ntile*2)*64 + lane)*8;
      #pragma unroll
      for (int ks = 0; ks < 2; ks++) {
        short8 bf = *(const short8*)(bb + ks*512);
        short8 af = *(const short8*)(ap + ks*32 + qr*8);
        c = __builtin_amdgcn_mfma_f32_16x16x32_bf16(af, bf, c, 0, 0, 0);
      }
      #pragma unroll
      for (int r = 0; r < 4; r++) {
        int row = qr*4 + r;
        if (row < 4) xosh[row*64 + ntile*16 + ml] = ush[row] * c[r];
      }
    }

    // coalesced float4 store of staged V_out: 4 edges x 144 f32x4
    for (int q = t; q < 576; q += 256) {
      int el = q / 144, i4 = q - (q/144)*144;
      ((f32x4*)(out + E64 + (size_t)(e0+el)*576))[i4] = ((f32x4*)(vosh + el*584))[i4];
    }
    __syncthreads();   // xosh ready

    // coalesced 1KB x_out store
    if (t < 64)
      ((f32x4*)(out + (size_t)e0*64))[t] = ((f32x4*)xosh)[t];

    __syncthreads();   // tile LDS (vosh/hsh/xosh) dead before next tile reuses
  }
}

extern "C" void kernel_launch(void* const* d_in, const int* in_sizes, int n_in,
                              void* d_out, int out_size, void* d_ws, size_t ws_size,
                              hipStream_t stream)
{
  const float* vec     = (const float*)d_in[0];
  const float* x       = (const float*)d_in[1];
  const float* V       = (const float*)d_in[2];
  const int*   senders = (const int*)  d_in[3];
  const float* Ww      = (const float*)d_in[4];
  const float* W1      = (const float*)d_in[5];
  const float* W2      = (const float*)d_in[6];
  const float* W3      = (const float*)d_in[7];
  const float* Wv1     = (const float*)d_in[8];
  const float* Wv2     = (const float*)d_in[9];
  float* out = (float*)d_out;
  const int E = in_sizes[0] / 3;

  static HostConsts HC;   // pure-CPU static init, no HIP calls

  // ---- workspace layout ----
  char* base = (char*)d_ws;
  float* node_agg = (float*)(base);                        // 4 MB  [node][n][k]
  float* w_ws     = (float*)(base + (4<<20));              // 4 MB
  int* counts     = (int*)  (base + (8<<20) + 8192);       // 4096 B
  int* bars       = (int*)  (base + (8<<20) + 12288);      // 128 B (2 used)
  int* elist      = (int*)  (base + (8<<20) + 16384);      // 256 KB -> ends at +278528
  unsigned short* wv1f = (unsigned short*)(base + (8<<20) + 278528);
  unsigned short* wv2f = (unsigned short*)(base + (8<<20) + 319488);
  unsigned short* w1f  = (unsigned short*)(base + (8<<20) + 360448);
  unsigned short* w2f  = (unsigned short*)(base + (8<<20) + 393216);
  unsigned short* w3f  = (unsigned short*)(base + (8<<20) + 401408);

  // one memset covers counts (4096 B) + barrier counters (128 B), contiguous
  hipMemsetAsync(counts, 0, 4096 + 128, stream);

  mega<<<GRID, 256, 0, stream>>>(vec, x, V, senders, Ww,
                                 Wv1, Wv2, W1, W2, W3,
                                 HC.pack, HC.inv_actc,
                                 node_agg, w_ws, counts, elist, bars,
                                 wv1f, wv2f, w1f, w2f, w3f, out, E);
}

// Round 6
// 158.926 us; speedup vs baseline: 3.1601x; 3.1601x over previous
//
#include <hip/hip_runtime.h>
#include <math.h>

#define NNODES 1024
#define EB 4   // edges per block in edge_main (one edge per wave in TP phase)

typedef __attribute__((ext_vector_type(8))) short short8;
typedef __attribute__((ext_vector_type(4))) float f32x4;

__device__ __forceinline__ unsigned short f2bf(float f) {
  union { float f; unsigned int u; } v; v.f = f;
  unsigned int r = v.u + 0x7fffu + ((v.u >> 16) & 1u);
  return (unsigned short)(r >> 16);
}

// =====================================================================
// Host-side constants (pure CPU at static init — no HIP calls, graph-safe).
// CG tensors in f64 (matches reference), 0.25 agg-scale folded in.
// Copied to a device buffer by one k_pre block (kernarg -> global).
// =====================================================================
struct CGPack { float v[576]; };

static const double H_SHC[16][2] = {
  {1.0, 0.0},
  {1.7320508075688772, 0.0},
  {1.7320508075688772, 0.0},
  {1.7320508075688772, 0.0},
  {3.8729833462074170, 0.0},
  {3.8729833462074170, 0.0},
  {3.3541019662496844, -1.1180339887498949},
  {3.8729833462074170, 0.0},
  {1.9364916731037085, -1.9364916731037085},
  {6.2749501990055667, -2.0916500663351889},
  {10.246950765959598, 0.0},
  {8.1009258730098255, -1.6201851746019651},
  {6.6143782776614768, -3.9686269665968861},
  {8.1009258730098255, -1.6201851746019651},
  {5.1234753829797990, -5.1234753829797990},
  {2.0916500663351889, -6.2749501990055667},
};
static const int H_SHE[16][2] = {     // exponents packed ex | ey<<4 | ez<<8
  {0,0},{1,0},{16,0},{256,0},
  {17,0},{272,0},{512,0},{257,0},{2,32},
  {18,48},{273,0},{528,16},{768,256},{513,1},{258,288},{3,33}};
static const int H_PL1[13] = {0,1,2, 0,1,1,2,3, 0,1,2,2,3};
static const int H_PL2[13] = {0,1,2, 1,0,2,1,2, 2,1,0,2,1};
static const int H_PL3[13] = {0,0,0, 1,1,1,1,1, 2,2,2,2,2};
static const int H_PCG[13] = {0,1,10, 35,44,53,98,143, 248,273,318,343,468};

static double h_dfact(int n) { double r = 1.0; while (n > 1) { r *= n; n -= 2; } return r; }

struct HostConsts {
  CGPack pack;
  float inv_actc;
  HostConsts() {
    const int LOFF[4] = {0,1,4,9};
    for (int p = 0; p < 13; p++) {
      int l1 = H_PL1[p], l2 = H_PL2[p], l3 = H_PL3[p];
      int n1 = 2*l1+1, n2 = 2*l2+1, n3 = 2*l3+1, nent = n1*n2*n3;
      double vals[125], ss = 0.0;
      for (int t = 0; t < nent; t++) {
        int i = t / (n2*n3);
        int rem = t - i*(n2*n3);
        int j = rem / n3;
        int k = rem - j*n3;
        int lm1 = LOFF[l1]+i, lm2 = LOFF[l2]+j, lm3 = LOFF[l3]+k;
        double v = 0.0;
        for (int t1 = 0; t1 < 2; t1++)
        for (int t2 = 0; t2 < 2; t2++)
        for (int t3 = 0; t3 < 2; t3++) {
          double cc = H_SHC[lm1][t1]*H_SHC[lm2][t2]*H_SHC[lm3][t3];
          if (cc == 0.0) continue;
          int s = H_SHE[lm1][t1] + H_SHE[lm2][t2] + H_SHE[lm3][t3];
          int a = s & 15, b = (s >> 4) & 15, c = (s >> 8) & 15;
          if (!((a|b|c) & 1))
            v += cc * (h_dfact(a-1)*h_dfact(b-1)*h_dfact(c-1) / h_dfact(a+b+c+1));
        }
        vals[t] = v; ss += v*v;
      }
      double scale = sqrt((double)(2*l3+1)) / sqrt(ss);
      for (int t = 0; t < nent; t++) pack.v[H_PCG[p]+t] = (float)(vals[t]*scale*0.25);
    }
    pack.v[573] = pack.v[574] = pack.v[575] = 0.f;
    double s = 0.0, dz = 24.0/200000.0;
    for (int i = 0; i <= 200000; i++) {
      double z = -12.0 + dz*i;
      double ph = exp(-0.5*z*z) * 0.39894228040143267794;
      double sl = z / (1.0 + exp(-z));
      s += sl*sl*ph;
    }
    inv_actc = (float)(1.0 / sqrt(s*dz));
  }
};

// =====================================================================
// k_pre — block ranges:
//   [0, nsc)            : edge->node scatter (counts pre-zeroed by memset)
//   [nsc, nsc+32)       : weight fragment pack (bf16, scales folded)
//   nsc+32              : copy CG pack kernarg -> global cgbuf
//   [nsc+33, +ngemm)    : w = x @ W_w / 8 in f32 (tiled, no shuffles)
// =====================================================================
__global__ __launch_bounds__(256) void k_pre(
    const int* __restrict__ senders, int* __restrict__ counts, int* __restrict__ elist,
    const float* __restrict__ x, const float* __restrict__ Ww,
    float* __restrict__ w_ws,
    const float* __restrict__ Wv1, const float* __restrict__ Wv2,
    const float* __restrict__ W1, const float* __restrict__ W2, const float* __restrict__ W3,
    unsigned short* __restrict__ wv1f, unsigned short* __restrict__ wv2f,
    unsigned short* __restrict__ w1f, unsigned short* __restrict__ w2f,
    unsigned short* __restrict__ w3f,
    const CGPack P, float* __restrict__ cgbuf,
    float inv_actc, int E)
{
  const int t = threadIdx.x;
  const int bid = blockIdx.x;
  const int nsc = (E + 255) >> 8;

  if (bid < nsc) {
    // ---- scatter ----
    int e = bid*256 + t;
    if (e < E) {
      int s = senders[e];
      int pos = atomicAdd(&counts[s], 1) & 63;  // P(deg>=64) ~ 1e-18 for Poisson(16)
      elist[s*64 + pos] = e;
    }
    return;
  }

  if (bid < nsc + 32) {
    // ---- weight fragment pack: 4 fragments per block ----
    const int wid = t >> 6, lane = t & 63;
    const int g = (bid - nsc)*4 + wid;
    const float ia = inv_actc;
    const float s320 = 0.05590169943749474f;  // 1/sqrt(320)
    const float* src; unsigned short* dst; int nk, f; float sc;
    if (g < 40)       { src = Wv1; dst = wv1f; nk = 10; f = g;       sc = s320; }
    else if (g < 80)  { src = Wv2; dst = wv2f; nk = 10; f = g - 40;  sc = s320; }
    else if (g < 112) { src = W1;  dst = w1f;  nk = 8;  f = g - 80;  sc = 0.0625f; }
    else if (g < 120) { src = W2;  dst = w2f;  nk = 2;  f = g - 112; sc = 0.125f*ia; }
    else              { src = W3;  dst = w3f;  nk = 2;  f = g - 120; sc = 0.125f*ia; }
    int nt = f / nk;
    int ks = f - nt*nk;
    unsigned short us[8];
    #pragma unroll
    for (int j = 0; j < 8; j++) {
      float v = src[(ks*32 + (lane>>4)*8 + j)*64 + nt*16 + (lane & 15)];
      us[j] = f2bf(v * sc);
    }
    uint4 pk;
    pk.x = (unsigned)us[0] | ((unsigned)us[1] << 16);
    pk.y = (unsigned)us[2] | ((unsigned)us[3] << 16);
    pk.z = (unsigned)us[4] | ((unsigned)us[5] << 16);
    pk.w = (unsigned)us[6] | ((unsigned)us[7] << 16);
    *(uint4*)(dst + ((size_t)f*64 + lane)*8) = pk;
    return;
  }

  if (bid == nsc + 32) {
    // ---- CG copy: kernarg -> global ----
    for (int i = t; i < 576; i += 256) cgbuf[i] = P.v[i];
    return;
  }

  // ---- w-GEMM: 64 edges x 64 outputs, K=64, f32 ----
  __shared__ float xsh[64*64];   // 16 KB
  const int eb0 = (bid - nsc - 33) * 64;
  for (int q = t; q < 1024; q += 256)
    ((f32x4*)xsh)[q] = ((const f32x4*)(x + (size_t)eb0*64))[q];

  const int n = t & 63;          // output feature owned by this thread
  float ww[64];
  #pragma unroll
  for (int f = 0; f < 64; f++) ww[f] = Ww[f*64 + n];   // coalesced, L1/L2-hot
  __syncthreads();

  const int er0 = (t >> 6) * 16; // wave wid handles edges er0..er0+15
  #pragma unroll
  for (int i = 0; i < 16; i++) {
    int e = er0 + i;
    const f32x4* xr = (const f32x4*)(&xsh[e*64]);  // broadcast reads
    float a0 = 0.f, a1 = 0.f, a2 = 0.f, a3 = 0.f;
    #pragma unroll
    for (int fq = 0; fq < 16; fq += 4) {
      f32x4 x0 = xr[fq+0], x1 = xr[fq+1], x2 = xr[fq+2], x3 = xr[fq+3];
      a0 = fmaf(x0.x, ww[fq*4+0],  fmaf(x0.y, ww[fq*4+1],  fmaf(x0.z, ww[fq*4+2],  fmaf(x0.w, ww[fq*4+3],  a0))));
      a1 = fmaf(x1.x, ww[fq*4+4],  fmaf(x1.y, ww[fq*4+5],  fmaf(x1.z, ww[fq*4+6],  fmaf(x1.w, ww[fq*4+7],  a1))));
      a2 = fmaf(x2.x, ww[fq*4+8],  fmaf(x2.y, ww[fq*4+9],  fmaf(x2.z, ww[fq*4+10], fmaf(x2.w, ww[fq*4+11], a2))));
      a3 = fmaf(x3.x, ww[fq*4+12], fmaf(x3.y, ww[fq*4+13], fmaf(x3.z, ww[fq*4+14], fmaf(x3.w, ww[fq*4+15], a3))));
    }
    w_ws[(size_t)(eb0+e)*64 + n] = ((a0+a1)+(a2+a3)) * 0.125f;
  }
}

// =====================================================================
// k_node: SH aggregation only (w precomputed). One block per node, 4 waves.
// node_agg layout: [node][n(64)][k(16)]
// =====================================================================
__global__ __launch_bounds__(256) void k_node(
    const float* __restrict__ vec, const float* __restrict__ w_ws,
    const int* __restrict__ counts, const int* __restrict__ elist,
    float* __restrict__ node_agg)
{
  __shared__ float red[4*1024];
  const int wid = threadIdx.x >> 6, lane = threadIdx.x & 63;
  const int s = blockIdx.x;
  const int deg = min(counts[s], 64);

  const float S3 = 1.7320508075688772f, S5 = 2.23606797749979f, S15 = 3.872983346207417f;
  const float C33 = 2.091650066335189f, C32 = 5.123475382979799f, C31 = 1.6201851746019651f;
  const float C30 = 1.3228756555322954f, CX = 10.246950765959598f;

  float A[16];
  #pragma unroll
  for (int k = 0; k < 16; k++) A[k] = 0.f;

  for (int ii = wid; ii < deg; ii += 4) {
    int e = elist[s*64 + ii];
    float wv = w_ws[(size_t)e*64 + lane];     // coalesced 256B/wave
    float vx = vec[e*3+0], vy = vec[e*3+1], vz = vec[e*3+2];
    float d = sqrtf(vx*vx + vy*vy + vz*vz);
    float X = vx/d, Yv = vy/d, Z = vz/d;
    float y[16];
    y[0] = 1.f;
    y[1] = S3*X;  y[2] = S3*Yv;  y[3] = S3*Z;
    y[4] = S15*X*Yv; y[5] = S15*Yv*Z; y[6] = 0.5f*S5*(3.f*Z*Z - 1.f);
    y[7] = S15*X*Z;  y[8] = 0.5f*S15*(X*X - Yv*Yv);
    y[9]  = C33*Yv*(3.f*X*X - Yv*Yv);
    y[10] = CX*X*Yv*Z;
    y[11] = C31*Yv*(5.f*Z*Z - 1.f);
    y[12] = C30*Z*(5.f*Z*Z - 3.f);
    y[13] = C31*X*(5.f*Z*Z - 1.f);
    y[14] = C32*Z*(X*X - Yv*Yv);
    y[15] = C33*X*(X*X - 3.f*Yv*Yv);
    #pragma unroll
    for (int k = 0; k < 16; k++) A[k] = fmaf(wv, y[k], A[k]);
  }
  #pragma unroll
  for (int k = 0; k < 16; k++) red[wid*1024 + lane*16 + k] = A[k];
  __syncthreads();
  const int t = threadIdx.x;
  f32x4 v0 = ((f32x4*)red)[t];
  f32x4 v1 = ((f32x4*)red)[256 + t];
  f32x4 v2 = ((f32x4*)red)[512 + t];
  f32x4 v3 = ((f32x4*)red)[768 + t];
  f32x4 sum = v0 + v1 + v2 + v3;
  ((f32x4*)(node_agg + (size_t)s*1024))[t] = sum;
}

// ---------------- TP helper: fully unrolled with compile-time parity masking ----
template<int L1, int L2, int L3>
__device__ __forceinline__ void tp_path(const float* __restrict__ cgp,
    const float a[16], const float b[9], float o[2*L3+1])
{
  constexpr int N1 = 2*L1+1, N2 = 2*L2+1, N3 = 2*L3+1;
  constexpr int AO = (L1==0) ? 0 : (L1==1) ? 1 : (L1==2) ? 4 : 9;
  constexpr int BO = (L2==0) ? 0 : (L2==1) ? 1 : 4;
  constexpr int LM1 = (L1==0) ? 0 : (L1==1) ? 1 : (L1==2) ? 4 : 9;
  constexpr int LM2 = (L2==0) ? 0 : (L2==1) ? 1 : 4;
  constexpr int LM3 = (L3==0) ? 0 : (L3==1) ? 1 : 4;
  static constexpr unsigned char PAR[16] =
      {0, 1,2,4, 3,6,0,5,0, 2,7,2,4,1,4,1};
  #pragma unroll
  for (int k = 0; k < N3; k++) o[k] = 0.f;
  int ci = 0;
  #pragma unroll
  for (int i = 0; i < N1; i++) {
    #pragma unroll
    for (int j = 0; j < N2; j++) {
      float ab = a[AO+i] * b[BO+j];
      #pragma unroll
      for (int k = 0; k < N3; k++) {
        if ((PAR[LM1+i] ^ PAR[LM2+j] ^ PAR[LM3+k]) == 0)
          o[k] = fmaf(ab, cgp[ci], o[k]);
        ci++;
      }
    }
  }
}

// =====================================================================
// main fused kernel — R2-proven body (52.7 us) + coalesced V staging:
// V loaded f32x4-coalesced into the upper half of V12sh (dead region
// until TP writes reach V2sh rows; protected by a barrier), then read
// per-lane from LDS (stride-9 dwords: conflict-free, 9 coprime 32).
// vosh f32 staging aliased over dead V12sh; accs held in VGPRs across
// the MLP1 barrier. LDS ~25 KB -> 6 blocks/CU.
// =====================================================================
__global__ __launch_bounds__(256, 6) void edge_main(
    const float* __restrict__ vec, const float* __restrict__ x,
    const float* __restrict__ V, const int* __restrict__ senders,
    const float* __restrict__ node_agg, const float* __restrict__ cg,
    const unsigned short* __restrict__ wv1f, const unsigned short* __restrict__ wv2f,
    const unsigned short* __restrict__ w1f, const unsigned short* __restrict__ w2f,
    const unsigned short* __restrict__ w3f,
    float* __restrict__ out, int E)
{
  __shared__ __align__(16) unsigned short V12sh[32*328]; // 20992 B
  __shared__ __align__(16) unsigned short zrow[336];
  __shared__ __align__(16) unsigned short hsh[4*264];
  __shared__ __align__(16) unsigned short h1sh[4*72];
  __shared__ __align__(16) unsigned short h2sh[4*72];
  __shared__ float ush[EB];

  unsigned short* V1sh = V12sh;
  unsigned short* V2sh = V12sh + 12*328;
  float* vosh = (float*)V12sh;            // 4*584 floats = 9344 B <= 20992 B
  float* vsta = ((float*)V12sh) + 2944;   // bytes 11776..20992: 2304 floats

  const int t = threadIdx.x;
  const int wid = t >> 6, lane = t & 63;
  const int e0 = blockIdx.x * EB;
  const size_t E64 = (size_t)E * 64;

  if (t < 168) ((unsigned int*)zrow)[t] = 0u;

  if (t < 64) {  // x -> hsh staging: 64 threads x 4 floats = 4 edges x 64 feats
    int el = t >> 4, off = (t & 15)*4;
    f32x4 xv = *(const f32x4*)(x + (size_t)(e0 + el)*64 + off);
    uint2 pk;
    pk.x = (unsigned)f2bf(xv.x) | ((unsigned)f2bf(xv.y) << 16);
    pk.y = (unsigned)f2bf(xv.z) | ((unsigned)f2bf(xv.w) << 16);
    *(uint2*)(hsh + el*264 + off) = pk;
  }

  // ---- V staging: 4 edges x 576 floats, fully coalesced f32x4 ----
  {
    const f32x4* vsrc = (const f32x4*)(V + (size_t)e0*576);
    f32x4* vdst = (f32x4*)vsta;
    for (int q = t; q < 576; q += 256) vdst[q] = vsrc[q];
  }
  __syncthreads();

  // ---- TP phase: one edge per wave ----
  {
    const int eloc = wid;
    const int eg = e0 + eloc;

    float b[9];
    #pragma unroll
    for (int j = 0; j < 9; j++) b[j] = vsta[eloc*576 + lane*9 + j];

    const int s = senders[eg];
    float a[16];
    const float* nap = node_agg + s*1024 + lane*16;
    #pragma unroll
    for (int k = 0; k < 16; k++) a[k] = nap[k];   // 0.25 folded into cg

    __syncthreads();   // all b[] reads done -> vsta region reusable by TP writes

    float o1[1], o3[3], o5[5];
    tp_path<0,0,0>(cg + 0,  a, b, o1); hsh[eloc*264 + 64 + lane*3 + 0] = f2bf(o1[0]);
    tp_path<1,1,0>(cg + 1,  a, b, o1); hsh[eloc*264 + 64 + lane*3 + 1] = f2bf(o1[0]);
    tp_path<2,2,0>(cg + 10, a, b, o1); hsh[eloc*264 + 64 + lane*3 + 2] = f2bf(o1[0]);
    tp_path<0,1,1>(cg + 35, a, b, o3);
    { int r = eloc*3; for (int i=0;i<3;i++) V1sh[(r+i)*328 + 0*64 + lane] = f2bf(o3[i]); }
    tp_path<1,0,1>(cg + 44, a, b, o3);
    { int r = eloc*3; for (int i=0;i<3;i++) V1sh[(r+i)*328 + 1*64 + lane] = f2bf(o3[i]); }
    tp_path<1,2,1>(cg + 53, a, b, o3);
    { int r = eloc*3; for (int i=0;i<3;i++) V1sh[(r+i)*328 + 2*64 + lane] = f2bf(o3[i]); }
    tp_path<2,1,1>(cg + 98, a, b, o3);
    { int r = eloc*3; for (int i=0;i<3;i++) V1sh[(r+i)*328 + 3*64 + lane] = f2bf(o3[i]); }
    tp_path<3,2,1>(cg + 143, a, b, o3);
    { int r = eloc*3; for (int i=0;i<3;i++) V1sh[(r+i)*328 + 4*64 + lane] = f2bf(o3[i]); }
    tp_path<0,2,2>(cg + 248, a, b, o5);
    { int r = eloc*5; for (int i=0;i<5;i++) V2sh[(r+i)*328 + 0*64 + lane] = f2bf(o5[i]); }
    tp_path<1,1,2>(cg + 273, a, b, o5);
    { int r = eloc*5; for (int i=0;i<5;i++) V2sh[(r+i)*328 + 1*64 + lane] = f2bf(o5[i]); }
    tp_path<2,0,2>(cg + 318, a, b, o5);
    { int r = eloc*5; for (int i=0;i<5;i++) V2sh[(r+i)*328 + 2*64 + lane] = f2bf(o5[i]); }
    tp_path<2,2,2>(cg + 343, a, b, o5);
    { int r = eloc*5; for (int i=0;i<5;i++) V2sh[(r+i)*328 + 3*64 + lane] = f2bf(o5[i]); }
    tp_path<3,1,2>(cg + 468, a, b, o5);
    { int r = eloc*5; for (int i=0;i<5;i++) V2sh[(r+i)*328 + 4*64 + lane] = f2bf(o5[i]); }

    if (lane == 0) {
      float vx = vec[eg*3+0], vy = vec[eg*3+1], vz = vec[eg*3+2];
      float d = sqrtf(vx*vx + vy*vy + vz*vz);
      float u = 0.f;
      if (d < 1.f) {
        float d3 = d*d*d, d6 = d3*d3, d7 = d6*d, d8 = d7*d;
        u = 1.f - 28.f*d6 + 48.f*d7 - 21.f*d8;
      }
      ush[eloc] = u;
    }
  }
  __syncthreads();

  // ---- MFMA GEMM phase: wave wid owns output-column tile ntile=wid (16 cols) ----
  const int ntile = wid;
  const int qr = lane >> 4;
  const int ml = lane & 15;

  // V1: M=12 (1 tile), K=320 (1/sqrt(320) folded into wv1f)
  f32x4 acc1 = (f32x4){0,0,0,0};
  {
    const unsigned short* p0 = (ml < 12) ? &V1sh[ml*328] : zrow;
    const unsigned short* bb = wv1f + ((size_t)(ntile*10)*64 + lane)*8;
    #pragma unroll
    for (int ks = 0; ks < 10; ks++) {
      short8 bf = *(const short8*)(bb + ks*512);
      short8 af = *(const short8*)(p0 + ks*32 + qr*8);
      acc1 = __builtin_amdgcn_mfma_f32_16x16x32_bf16(af, bf, acc1, 0, 0, 0);
    }
  }

  // V2: M=20 (2 tiles), K=320
  f32x4 acc2a = (f32x4){0,0,0,0}, acc2b = (f32x4){0,0,0,0};
  {
    const unsigned short* p0 = &V2sh[ml*328];
    const unsigned short* p1 = (16+ml < 20) ? &V2sh[(16+ml)*328] : zrow;
    const unsigned short* bb = wv2f + ((size_t)(ntile*10)*64 + lane)*8;
    #pragma unroll
    for (int ks = 0; ks < 10; ks++) {
      short8 bf = *(const short8*)(bb + ks*512);
      int ao = ks*32 + qr*8;
      short8 af0 = *(const short8*)(p0 + ao);
      short8 af1 = *(const short8*)(p1 + ao);
      acc2a = __builtin_amdgcn_mfma_f32_16x16x32_bf16(af0, bf, acc2a, 0, 0, 0);
      acc2b = __builtin_amdgcn_mfma_f32_16x16x32_bf16(af1, bf, acc2b, 0, 0, 0);
    }
  }

  // ---- MLP layer 1 (1/16 folded into w1f) ----
  const unsigned short* hp = (ml < 4) ? &hsh[ml*264] : zrow;
  {
    f32x4 c = (f32x4){0,0,0,0};
    const unsigned short* bb = w1f + ((size_t)(ntile*8)*64 + lane)*8;
    #pragma unroll
    for (int ks = 0; ks < 8; ks++) {
      short8 bf = *(const short8*)(bb + ks*512);
      short8 af = *(const short8*)(hp + ks*32 + qr*8);
      c = __builtin_amdgcn_mfma_f32_16x16x32_bf16(af, bf, c, 0, 0, 0);
    }
    #pragma unroll
    for (int r = 0; r < 4; r++) {
      int row = qr*4 + r;
      if (row < 4) {
        float v = c[r];
        float sv = v / (1.f + expf(-v));       // inv_actc folded into w2f
        h1sh[row*72 + ntile*16 + ml] = f2bf(sv);
      }
    }
  }
  __syncthreads();   // h1sh ready; ALL waves done reading V1sh/V2sh

  // ---- vosh staging over dead V12sh ----
  #pragma unroll
  for (int r = 0; r < 4; r++) {
    int row = qr*4 + r;
    if (row < 12) {
      int el = row / 3, i = row - (row/3)*3;
      vosh[el*584 + (ntile*16+ml)*9 + 1 + i] = acc1[r];
    }
  }
  #pragma unroll
  for (int r = 0; r < 4; r++) {
    int row = qr*4 + r;     // 0..15, all < 20
    int el = row / 5, i = row - (row/5)*5;
    vosh[el*584 + (ntile*16+ml)*9 + 4 + i] = acc2a[r];
  }
  #pragma unroll
  for (int r = 0; r < 4; r++) {
    int row = 16 + qr*4 + r;
    if (row < 20) {
      int el = row / 5, i = row - (row/5)*5;
      vosh[el*584 + (ntile*16+ml)*9 + 4 + i] = acc2b[r];
    }
  }
  { int el = t >> 6, o = t & 63;
    vosh[el*584 + o*9] = 0.f; }   // V_out channel 0 = 0

  // ---- MLP layer 2 (0.125*inv_actc folded into w2f) ----
  {
    f32x4 c = (f32x4){0,0,0,0};
    const unsigned short* ap = (ml < 4) ? &h1sh[ml*72] : zrow;
    const unsigned short* bb = w2f + ((size_t)(ntile*2)*64 + lane)*8;
    #pragma unroll
    for (int ks = 0; ks < 2; ks++) {
      short8 bf = *(const short8*)(bb + ks*512);
      short8 af = *(const short8*)(ap + ks*32 + qr*8);
      c = __builtin_amdgcn_mfma_f32_16x16x32_bf16(af, bf, c, 0, 0, 0);
    }
    #pragma unroll
    for (int r = 0; r < 4; r++) {
      int row = qr*4 + r;
      if (row < 4) {
        float v = c[r];
        float sv = v / (1.f + expf(-v));       // inv_actc folded into w3f
        h2sh[row*72 + ntile*16 + ml] = f2bf(sv);
      }
    }
  }
  __syncthreads();   // h2sh + vosh ready

  // ---- MLP layer 3 -> direct x_out store ----
  {
    f32x4 c = (f32x4){0,0,0,0};
    const unsigned short* ap = (ml < 4) ? &h2sh[ml*72] : zrow;
    const unsigned short* bb = w3f + ((size_t)(ntile*2)*64 + lane)*8;
    #pragma unroll
    for (int ks = 0; ks < 2; ks++) {
      short8 bf = *(const short8*)(bb + ks*512);
      short8 af = *(const short8*)(ap + ks*32 + qr*8);
      c = __builtin_amdgcn_mfma_f32_16x16x32_bf16(af, bf, c, 0, 0, 0);
    }
    #pragma unroll
    for (int r = 0; r < 4; r++) {
      int row = qr*4 + r;
      if (row < 4) {
        out[(size_t)(e0+row)*64 + ntile*16 + ml] = ush[row] * c[r];
      }
    }
  }

  // coalesced float4 store of staged V_out: 4 edges x 144 f32x4
  for (int q = t; q < 576; q += 256) {
    int el = q / 144, i4 = q - (q/144)*144;
    ((f32x4*)(out + E64 + (size_t)(e0+el)*576))[i4] = ((f32x4*)(vosh + el*584))[i4];
  }
}

extern "C" void kernel_launch(void* const* d_in, const int* in_sizes, int n_in,
                              void* d_out, int out_size, void* d_ws, size_t ws_size,
                              hipStream_t stream)
{
  const float* vec     = (const float*)d_in[0];
  const float* x       = (const float*)d_in[1];
  const float* V       = (const float*)d_in[2];
  const int*   senders = (const int*)  d_in[3];
  const float* Ww      = (const float*)d_in[4];
  const float* W1      = (const float*)d_in[5];
  const float* W2      = (const float*)d_in[6];
  const float* W3      = (const float*)d_in[7];
  const float* Wv1     = (const float*)d_in[8];
  const float* Wv2     = (const float*)d_in[9];
  float* out = (float*)d_out;
  const int E = in_sizes[0] / 3;

  static HostConsts HC;   // pure-CPU static init, no HIP calls

  // ---- workspace layout ----
  char* base = (char*)d_ws;
  float* node_agg = (float*)(base);                        // 4 MB  [node][n][k]
  float* w_ws     = (float*)(base + (4<<20));              // 4 MB
  float* cgbuf    = (float*)(base + (8<<20));              // 2304 B
  int* counts     = (int*)  (base + (8<<20) + 8192);       // 4096 B
  int* elist      = (int*)  (base + (8<<20) + 16384);      // 256 KB -> ends at +278528
  unsigned short* wv1f = (unsigned short*)(base + (8<<20) + 278528);
  unsigned short* wv2f = (unsigned short*)(base + (8<<20) + 319488);
  unsigned short* w1f  = (unsigned short*)(base + (8<<20) + 360448);
  unsigned short* w2f  = (unsigned short*)(base + (8<<20) + 393216);
  unsigned short* w3f  = (unsigned short*)(base + (8<<20) + 401408);

  hipMemsetAsync(counts, 0, NNODES*sizeof(int), stream);

  const int nsc = (E + 255) >> 8;
  const int ngemm = (E + 63) >> 6;
  k_pre<<<nsc + 33 + ngemm, 256, 0, stream>>>(senders, counts, elist,
                                      x, Ww, w_ws,
                                      Wv1, Wv2, W1, W2, W3,
                                      wv1f, wv2f, w1f, w2f, w3f,
                                      HC.pack, cgbuf, HC.inv_actc, E);
  k_node<<<NNODES, 256, 0, stream>>>(vec, w_ws, counts, elist, node_agg);
  edge_main<<<E/EB, 256, 0, stream>>>(vec, x, V, senders, node_agg, cgbuf,
                                      wv1f, wv2f, w1f, w2f, w3f, out, E);
}